// Round 2
// baseline (167.293 us; speedup 1.0000x reference)
//
#include <hip/hip_runtime.h>
#include <math.h>

#define N_     256
#define C_     2048
#define HW_    49
#define CHUNKS 4
#define CPB    (C_/CHUNKS)   // 512 channels per block
#define CPW    (CPB/4)       // 128 channels per wave
#define NG     5             // groups: sum, u0, u1, t0, t1

// ---------------------------------------------------------------------------
// Kernel 1: 5 weighted channel-reductions, no LDS staging.
// lane = position p (49 active of 64); channel loop is wave-uniform so the
// 4 weight loads scalarize to s_load; x load is 49 consecutive dwords/instr.
// part[n][chunk][g*49+p] = sum over chunk's channels of x[n,c,p]*w_g[c]
//   w_0 = 1, w_1 = W[0,c], w_2 = W[1,c], w_3 = W[0,C+c], w_4 = W[1,C+c]
// ---------------------------------------------------------------------------
__global__ __launch_bounds__(256) void k_dot(const float* __restrict__ x,
                                             const float* __restrict__ Wm,
                                             float* __restrict__ part) {
  const int chunk = blockIdx.x;   // 0..3
  const int n     = blockIdx.y;   // 0..255
  const int t     = threadIdx.x;
  const int w     = t >> 6;       // wave 0..3
  const int l     = t & 63;       // lane; p = l when l < 49

  __shared__ float red[4][NG][HW_ + 7];   // +7 pad, tiny anyway

  const int cbase = chunk*CPB + w*CPW;    // wave-uniform
  // lanes >= 49 read a safe in-range address (p=0) and are discarded at store
  const float* xq   = x + ((size_t)n*C_ + cbase)*HW_ + (l < HW_ ? l : 0);
  const float* w_u0 = Wm + cbase;             // W[0, c]
  const float* w_u1 = Wm + 2*C_ + cbase;      // W[1, c]
  const float* w_t0 = Wm + C_ + cbase;        // W[0, C+c]
  const float* w_t1 = Wm + 3*C_ + cbase;      // W[1, C+c]

  float a0=0.f, a1=0.f, a2=0.f, a3=0.f, a4=0.f;
  #pragma unroll 8
  for (int c = 0; c < CPW; ++c) {
    const float xv = xq[(size_t)c*HW_];
    const float b0 = w_u0[c];   // wave-uniform -> SGPR
    const float b1 = w_u1[c];
    const float b2 = w_t0[c];
    const float b3 = w_t1[c];
    a0 += xv;
    a1 = fmaf(xv, b0, a1);
    a2 = fmaf(xv, b1, a2);
    a3 = fmaf(xv, b2, a3);
    a4 = fmaf(xv, b3, a4);
  }

  if (l < HW_) {
    red[w][0][l] = a0; red[w][1][l] = a1; red[w][2][l] = a2;
    red[w][3][l] = a3; red[w][4][l] = a4;
  }
  __syncthreads();

  if (t < NG*HW_) {
    const int g = t / HW_, p = t - g*HW_;
    const float s = red[0][g][p] + red[1][g][p] + red[2][g][p] + red[3][g][p];
    part[((size_t)n*CHUNKS + chunk)*(NG*HW_) + t] = s;
  }
}

// ---------------------------------------------------------------------------
// Kernel 2: per-n epilogue. One block per n.
// ---------------------------------------------------------------------------
__global__ __launch_bounds__(256) void k_final(const float* __restrict__ part,
                                               const float* __restrict__ mask,
                                               const float* __restrict__ b,
                                               float* __restrict__ out) {
  const int n = blockIdx.x;
  const int t = threadIdx.x;
  __shared__ float red[NG*HW_];

  if (t < NG*HW_) {
    float a = 0.f;
    #pragma unroll
    for (int ch = 0; ch < CHUNKS; ++ch)
      a += part[((size_t)n*CHUNKS + ch)*(NG*HW_) + t];
    red[t] = a;
  }
  __syncthreads();

  if (t < 64) {
    const int  p   = t;
    const bool act = (p < HW_);

    // threshold = mean(mask[n]); binary mask strict >
    float m = act ? mask[n*HW_ + p] : 0.f;
    float tot = m;
    #pragma unroll
    for (int off = 32; off; off >>= 1) tot += __shfl_xor(tot, off);
    const float thr = tot / 49.f;

    // masked_mean and first-index argmax over 49 positions
    float s  = act ? red[0*HW_ + p] : 0.f;
    float mm = act ? ((m > thr) ? (s * (1.f/2048.f)) : 0.f) : -INFINITY;
    float best = mm;
    int   bidx = act ? p : 64;
    #pragma unroll
    for (int off = 32; off; off >>= 1) {
      float ov = __shfl_xor(best, off);
      int   oi = __shfl_xor(bidx, off);
      if (ov > best || (ov == best && oi < bidx)) { best = ov; bidx = oi; }
    }
    const int mi = bidx;   // uniform across wave

    const float u0mi = red[1*HW_ + mi];
    const float u1mi = red[2*HW_ + mi];

    float pred0 = 0.f, pred1 = 0.f;
    if (act) {
      pred0 = fmaxf(u0mi + red[3*HW_ + p] + b[0], 0.f);
      pred1 = fmaxf(u1mi + red[4*HW_ + p] + b[1], 0.f);
      if (p == mi) { pred0 = 0.f; pred1 = 0.f; }
    }

    // geometry
    const int ii = p / 7,  jj = p - ii*7;
    const int ai = mi / 7, aj = mi - ai*7;
    const float ri = (float)(ii - ai) / 7.f;
    const float rj = (float)(jj - aj) / 7.f;
    const float dist = sqrtf(ri*ri + rj*rj);
    const float ang  = (atan2f(rj, ri) / 3.14159274101257324f + 1.f) * 0.5f;

    float gap = pred1 - ang;
    if (gap < 0.f) gap += 1.f;
    float gsum = act ? gap : 0.f;
    #pragma unroll
    for (int off = 32; off; off >>= 1) gsum += __shfl_xor(gsum, off);
    const float gmean = gsum / 49.f;

    if (act) {
      const float dl = pred0 - dist;
      const float ga = gap - gmean;
      out[n*HW_ + p] = dl*dl + ga*ga;
    }
  }
}

extern "C" void kernel_launch(void* const* d_in, const int* in_sizes, int n_in,
                              void* d_out, int out_size, void* d_ws, size_t ws_size,
                              hipStream_t stream) {
  const float* x    = (const float*)d_in[0];  // (256, 2048, 7, 7)
  const float* mask = (const float*)d_in[1];  // (256, 7, 7)
  const float* Wm   = (const float*)d_in[2];  // (2, 4096)
  const float* b    = (const float*)d_in[3];  // (2,)
  float* out  = (float*)d_out;                // (256, 7, 7)
  float* part = (float*)d_ws;                 // 256*4*245 floats = 1.0 MB

  dim3 g1(CHUNKS, N_);
  k_dot<<<g1, 256, 0, stream>>>(x, Wm, part);
  k_final<<<N_, 256, 0, stream>>>(part, mask, b, out);
}

// Round 3
// 166.603 us; speedup vs baseline: 1.0041x; 1.0041x over previous
//
#include <hip/hip_runtime.h>
#include <math.h>

#define N_     256
#define C_     2048
#define HW_    49
#define WAVES  16
#define CPW    (C_/WAVES)    // 128 channels per wave
#define NG     5             // groups: sum, u0, u1, t0, t1
#define LDW    52            // padded row

// ---------------------------------------------------------------------------
// Fused kernel: one block per batch element n. 16 waves x 128 channels each,
// 5 register accumulators per lane (lane = position p, 49 active).
// Wave-partials -> LDS -> combine -> in-block epilogue (threshold, argmax,
// preds, geometry, gap-mean, output). No workspace, single dispatch.
// ---------------------------------------------------------------------------
__global__ __launch_bounds__(1024) void k_fused(const float* __restrict__ x,
                                                const float* __restrict__ mask,
                                                const float* __restrict__ Wm,
                                                const float* __restrict__ bias,
                                                float* __restrict__ out) {
  const int n = blockIdx.x;
  const int t = threadIdx.x;
  const int w = t >> 6;        // wave 0..15
  const int l = t & 63;        // lane; p = l when l < 49

  __shared__ float red[WAVES][NG][LDW];  // 16.6 KB wave partials
  __shared__ float fin[NG][HW_];         // combined

  const int cbase = w * CPW;
  const float* xq   = x + ((size_t)n*C_ + cbase)*HW_ + (l < HW_ ? l : 0);
  const float* w_u0 = Wm + cbase;             // W[0, c]
  const float* w_u1 = Wm + 2*C_ + cbase;      // W[1, c]
  const float* w_t0 = Wm + C_ + cbase;        // W[0, C+c]
  const float* w_t1 = Wm + 3*C_ + cbase;      // W[1, C+c]

  float a0=0.f, a1=0.f, a2=0.f, a3=0.f, a4=0.f;
  #pragma unroll 16
  for (int c = 0; c < CPW; ++c) {
    const float xv = xq[(size_t)c*HW_];
    const float b0 = w_u0[c];
    const float b1 = w_u1[c];
    const float b2 = w_t0[c];
    const float b3 = w_t1[c];
    a0 += xv;
    a1 = fmaf(xv, b0, a1);
    a2 = fmaf(xv, b1, a2);
    a3 = fmaf(xv, b2, a3);
    a4 = fmaf(xv, b3, a4);
  }

  if (l < HW_) {
    red[w][0][l] = a0; red[w][1][l] = a1; red[w][2][l] = a2;
    red[w][3][l] = a3; red[w][4][l] = a4;
  }
  __syncthreads();

  if (t < NG*HW_) {
    const int g = t / HW_, p = t - g*HW_;
    float s = 0.f;
    #pragma unroll
    for (int j = 0; j < WAVES; ++j) s += red[j][g][p];
    fin[g][p] = s;
  }
  __syncthreads();

  if (t < 64) {
    const int  p   = t;
    const bool act = (p < HW_);

    // threshold = mean(mask[n]); binary mask strict >
    float m = act ? mask[n*HW_ + p] : 0.f;
    float tot = m;
    #pragma unroll
    for (int off = 32; off; off >>= 1) tot += __shfl_xor(tot, off);
    const float thr = tot / 49.f;

    // masked_mean (zeros where mask==0) and first-index argmax
    float s  = act ? fin[0][p] : 0.f;
    float mm = act ? ((m > thr) ? (s * (1.f/2048.f)) : 0.f) : -INFINITY;
    float best = mm;
    int   bidx = act ? p : 64;
    #pragma unroll
    for (int off = 32; off; off >>= 1) {
      float ov = __shfl_xor(best, off);
      int   oi = __shfl_xor(bidx, off);
      if (ov > best || (ov == best && oi < bidx)) { best = ov; bidx = oi; }
    }
    const int mi = bidx;   // uniform across wave

    const float u0mi = fin[1][mi];
    const float u1mi = fin[2][mi];

    float pred0 = 0.f, pred1 = 0.f;
    if (act) {
      pred0 = fmaxf(u0mi + fin[3][p] + bias[0], 0.f);
      pred1 = fmaxf(u1mi + fin[4][p] + bias[1], 0.f);
      if (p == mi) { pred0 = 0.f; pred1 = 0.f; }
    }

    // geometry
    const int ii = p / 7,  jj = p - ii*7;
    const int ai = mi / 7, aj = mi - ai*7;
    const float ri = (float)(ii - ai) / 7.f;
    const float rj = (float)(jj - aj) / 7.f;
    const float dist = sqrtf(ri*ri + rj*rj);
    const float ang  = (atan2f(rj, ri) / 3.14159274101257324f + 1.f) * 0.5f;

    float gap = pred1 - ang;
    if (gap < 0.f) gap += 1.f;
    float gsum = act ? gap : 0.f;
    #pragma unroll
    for (int off = 32; off; off >>= 1) gsum += __shfl_xor(gsum, off);
    const float gmean = gsum / 49.f;

    if (act) {
      const float dl = pred0 - dist;
      const float ga = gap - gmean;
      out[n*HW_ + p] = dl*dl + ga*ga;
    }
  }
}

extern "C" void kernel_launch(void* const* d_in, const int* in_sizes, int n_in,
                              void* d_out, int out_size, void* d_ws, size_t ws_size,
                              hipStream_t stream) {
  const float* x    = (const float*)d_in[0];  // (256, 2048, 7, 7)
  const float* mask = (const float*)d_in[1];  // (256, 7, 7)
  const float* Wm   = (const float*)d_in[2];  // (2, 4096)
  const float* b    = (const float*)d_in[3];  // (2,)
  float* out = (float*)d_out;                 // (256, 7, 7)

  k_fused<<<N_, 1024, 0, stream>>>(x, mask, Wm, b, out);
}